// Round 18
// baseline (50.209 us; speedup 1.0000x reference)
//
#include <hip/hip_runtime.h>
#include <math.h>

#define DD 128
#define NSPLIT 16
#define NBINS 512
#define SHIFT 10.0f
#define L2E_T 14.4269504089f   // 10 * log2(e)

#define AS1 __attribute__((address_space(1)))
#define AS3 __attribute__((address_space(3)))

typedef _Float16 f16x8 __attribute__((ext_vector_type(8)));
typedef _Float16 f16x2 __attribute__((ext_vector_type(2)));
typedef float f32x4 __attribute__((ext_vector_type(4)));

// guard-free 2^x: args are in [-29, 0], no denorm/overflow concerns
__device__ __forceinline__ float ex2(float x) {
#if __has_builtin(__builtin_amdgcn_exp2f)
    return __builtin_amdgcn_exp2f(x);
#else
    return exp2f(x);
#endif
}

// ---- tiny zero: hist (512 ints) + d_out; 1 block, ~1us ----
__global__ __launch_bounds__(256)
void zero_kernel(int* __restrict__ hist, float* __restrict__ out)
{
    hist[threadIdx.x] = 0;
    hist[256 + threadIdx.x] = 0;
    if (threadIdx.x == 0) out[0] = 0.f;
}

// ---- normalize rows -> f16, labels, histogram ----
__global__ __launch_bounds__(256)
void norm_kernel(const float* __restrict__ f, const int* __restrict__ labels,
                 _Float16* __restrict__ fh, int* __restrict__ labm,
                 int* __restrict__ hist, int M, int nrep)
{
    int gw = (blockIdx.x * 256 + threadIdx.x) >> 6;   // one wave per row
    int lane = threadIdx.x & 63;
    if (gw >= M) return;
    float2 v = *reinterpret_cast<const float2*>(&f[(size_t)gw * DD + lane * 2]);
    float ss = v.x * v.x + v.y * v.y;
    #pragma unroll
    for (int m = 1; m < 64; m <<= 1) ss += __shfl_xor(ss, m);
    float inv = 1.0f / fmaxf(sqrtf(ss), 1e-12f);
    f16x2 h; h[0] = (_Float16)(v.x * inv); h[1] = (_Float16)(v.y * inv);
    *reinterpret_cast<f16x2*>(&fh[(size_t)gw * DD + lane * 2]) = h;
    if (lane == 0) {
        int lb = labels[gw / nrep];
        labm[gw] = lb;
        if ((gw % nrep) == 0) atomicAdd(&hist[lb], nrep);  // one atomic per sample
    }
}

// ---- main: f16 MFMA, global_load_lds staging, 32-row waves @ 4/SIMD ----
// Change vs R17: wave owns 32 i-rows (bfr[2][4] = 32 regs) instead of 64,
// halving the per-wave register footprint (~100 regs) so (256,4) fits
// honestly -> 4 blocks/CU, 4 waves/SIMD (R17 ran at 25% occupancy, 56%
// pure stall; all ILP-widening attempts spilled). LDS-DMA staging is
// register-free (the reason R8's 4-wave attempt degenerated is gone).
// NSPLIT=16 -> uniform 32-subtile chunks, 8 batches, no tails, no clamps.
// Paired subtile phases as R17 (acc 16 regs, af 16-reg LDS transient).
// Layout rule-21: linear DMA dest + inverse-swizzled global source + same
// XOR on ds_read (involution) -> 2-way bank = free.
// Self-pair included; final kernel subtracts it exactly.
__global__ __launch_bounds__(256, 4)
void supcon_main(const _Float16* __restrict__ fh, const int* __restrict__ labm,
                 float* __restrict__ Epart, float* __restrict__ Ppart,
                 int M, int jchunk)
{
    __shared__ float4 jbuf[2][1024];   // 2 x (64 rows x 16 chunks of 16B)

    const int tid = threadIdx.x;
    const int lane = tid & 63;
    const int w = tid >> 6;
    const int ibase = blockIdx.x * 128 + w * 32;
    const int rowsel = lane & 15;
    const int grp = lane >> 4;
    const int ksel = grp * 8;      // f16 k-offset within a 32-wide K step

    // register-resident Fi fragments: 2 subtiles x 4 K-steps = 32 regs
    f16x8 bfr[2][4];
    #pragma unroll
    for (int t = 0; t < 2; ++t)
        #pragma unroll
        for (int kk = 0; kk < 4; ++kk)
            bfr[t][kk] = *reinterpret_cast<const f16x8*>(
                &fh[(size_t)(ibase + t * 16 + rowsel) * DD + kk * 32 + ksel]);

    int li[2];
    #pragma unroll
    for (int t = 0; t < 2; ++t) li[t] = labm[ibase + t * 16 + rowsel];

    float esum[2] = {0.f, 0.f};
    float psum[2] = {0.f, 0.f};

    const int by = blockIdx.y;
    const int j0row = by * jchunk;        // uniform chunk: 512 rows
    const int nb = jchunk / 64;           // 8 batches of 4 subtiles

    // staging geometry: wave w, instr p covers LDS slots [(p*4+w)*64, +64);
    // slot s holds global chunk (row = s>>4, c = (s&15) ^ ((s>>4)&7)) so the
    // linear DMA write produces the swizzled layout the reader expects.
    int srow[4], scol[4];
    #pragma unroll
    for (int p = 0; p < 4; ++p) {
        int s = (p * 4 + w) * 64 + lane;
        srow[p] = s >> 4;                          // batch-local row 0..63
        scol[p] = ((s & 15) ^ ((s >> 4) & 7)) * 8; // f16 offset of source chunk
    }

#define STAGE(bb, tt) { \
    const int rb = j0row + (tt) * 64; \
    _Pragma("unroll") for (int p = 0; p < 4; ++p) { \
        const _Float16* gsrc = fh + (size_t)(rb + srow[p]) * DD + scol[p]; \
        __builtin_amdgcn_global_load_lds((const AS1 void*)gsrc, \
            (AS3 void*)&jbuf[bb][(p * 4 + w) * 64], 16, 0, 0); } }

#define LDSAF(bb, k) { \
    _Pragma("unroll") for (int kk = 0; kk < 4; ++kk) { \
        int slot = ((k) * 16 + rowsel) * 16 + ((kk * 4 + grp) ^ (rowsel & 7)); \
        af[kk] = *reinterpret_cast<const f16x8*>(&jbuf[bb][slot]); } }

#define MFMA8(A, c0, c1) { \
    _Pragma("unroll") for (int kk = 0; kk < 4; ++kk) { \
        c0 = __builtin_amdgcn_mfma_f32_16x16x32_f16(A[kk], bfr[0][kk], c0, 0, 0, 0); \
        c1 = __builtin_amdgcn_mfma_f32_16x16x32_f16(A[kk], bfr[1][kk], c1, 0, 0, 0); } }

#define EPI1(t, cc, L) { \
    esum[t] += (ex2(__builtin_fmaf(cc[0], L2E_T, -L2E_T)) \
              + ex2(__builtin_fmaf(cc[1], L2E_T, -L2E_T))) \
             + (ex2(__builtin_fmaf(cc[2], L2E_T, -L2E_T)) \
              + ex2(__builtin_fmaf(cc[3], L2E_T, -L2E_T))); \
    float p0 = (L.x == li[t]) ? cc[0] : 0.f; \
    float p1 = (L.y == li[t]) ? cc[1] : 0.f; \
    float p2 = (L.z == li[t]) ? cc[2] : 0.f; \
    float p3 = (L.w == li[t]) ? cc[3] : 0.f; \
    psum[t] += (p0 + p1) + (p2 + p3); }

// paired phase: two subtiles k0,k1 of batch tt; af reused (16-reg transient)
#define PAIR(bb, tt, k0, k1) { \
    f16x8 af[4]; \
    LDSAF(bb, k0); \
    f32x4 A0 = {0,0,0,0}, A1 = {0,0,0,0}; \
    MFMA8(af, A0, A1); \
    LDSAF(bb, k1); \
    f32x4 B0 = {0,0,0,0}, B1 = {0,0,0,0}; \
    MFMA8(af, B0, B1); \
    const int4 lj0 = *reinterpret_cast<const int4*>( \
        &labm[j0row + ((tt) * 4 + (k0)) * 16 + grp * 4]); \
    const int4 lj1 = *reinterpret_cast<const int4*>( \
        &labm[j0row + ((tt) * 4 + (k1)) * 16 + grp * 4]); \
    EPI1(0, A0, lj0); EPI1(1, A1, lj0); \
    EPI1(0, B0, lj1); EPI1(1, B1, lj1); }

    STAGE(0, 0);
    __syncthreads();                         // drain batch-0 DMA + barrier
    for (int t = 0; t < nb; ++t) {
        if (t + 1 < nb) STAGE((t + 1) & 1, t + 1);   // DMA next batch
        PAIR(t & 1, t, 0, 1);                // compute covers DMA latency
        PAIR(t & 1, t, 2, 3);
        __syncthreads();                     // drain DMA + readers done
    }
#undef STAGE
#undef LDSAF
#undef MFMA8
#undef EPI1
#undef PAIR

    // fold lane groups (bits 4,5 = different j rows of the same i)
    #pragma unroll
    for (int t = 0; t < 2; ++t) {
        float e = esum[t], p = psum[t];
        e += __shfl_xor(e, 16); e += __shfl_xor(e, 32);
        p += __shfl_xor(p, 16); p += __shfl_xor(p, 32);
        if (lane < 16) {
            size_t o = (size_t)by * M + ibase + t * 16 + lane;
            Epart[o] = e;
            Ppart[o] = p;
        }
    }
}

// ---- per-row loss term: one thread per row, coalesced partial reads,
// block-reduce, one atomic per block ----
__global__ __launch_bounds__(256)
void final_fused(const _Float16* __restrict__ fh, const float* __restrict__ Epart,
                 const float* __restrict__ Ppart, const int* __restrict__ labm,
                 const int* __restrict__ hist, float* __restrict__ out, int M)
{
    __shared__ float red[4];
    const int i = blockIdx.x * 256 + threadIdx.x;   // one row per thread
    float aii = 0.f;
    const f16x8* fr = reinterpret_cast<const f16x8*>(&fh[(size_t)i * DD]);
    #pragma unroll
    for (int k = 0; k < 16; ++k) {
        f16x8 hv = fr[k];
        #pragma unroll
        for (int e = 0; e < 8; ++e) {
            float x = (float)hv[e];
            aii = __builtin_fmaf(x, x, aii);
        }
    }
    float E = 0.f, P = 0.f;
    #pragma unroll
    for (int k = 0; k < NSPLIT; ++k) {
        E += Epart[(size_t)k * M + i];
        P += Ppart[(size_t)k * M + i];
    }
    int lb = labm[i];
    float cnt = (float)(hist[lb] - 1);
    E -= ex2(__builtin_fmaf(aii, L2E_T, -L2E_T));   // drop self exp
    float term = (SHIFT + logf(E)) - SHIFT * (P - aii) / cnt;

    #pragma unroll
    for (int m = 1; m < 64; m <<= 1) term += __shfl_xor(term, m);
    int lane = threadIdx.x & 63, wv = threadIdx.x >> 6;
    if (lane == 0) red[wv] = term;
    __syncthreads();
    if (threadIdx.x == 0)
        atomicAdd(out, (red[0] + red[1] + red[2] + red[3]) / (float)M);
}

extern "C" void kernel_launch(void* const* d_in, const int* in_sizes, int n_in,
                              void* d_out, int out_size, void* d_ws, size_t ws_size,
                              hipStream_t stream)
{
    const float* feats = (const float*)d_in[0];
    const int* labels = (const int*)d_in[1];
    const int Bn = in_sizes[1];
    const int M = in_sizes[0] / DD;    // 8192
    const int nrep = M / Bn;           // 2

    char* ws = (char*)d_ws;
    _Float16* fh = (_Float16*)ws;
    size_t off = (size_t)M * DD * sizeof(_Float16);
    int* labm = (int*)(ws + off); off += (size_t)M * sizeof(int);
    int* hist = (int*)(ws + off); off += (size_t)NBINS * sizeof(int);
    off = (off + 255) & ~(size_t)255;
    float* Epart = (float*)(ws + off); off += (size_t)NSPLIT * M * sizeof(float);
    float* Ppart = (float*)(ws + off); off += (size_t)NSPLIT * M * sizeof(float);

    zero_kernel<<<1, 256, 0, stream>>>(hist, (float*)d_out);

    norm_kernel<<<M / 4, 256, 0, stream>>>(feats, labels, fh, labm, hist, M, nrep);

    const int jchunk = M / NSPLIT;     // 512 rows = 32 subtiles = 8 batches
    dim3 grid(M / 128, NSPLIT);        // 64 x 16 = 1024 blocks (4/CU, 1 round)
    supcon_main<<<grid, 256, 0, stream>>>(fh, labm, Epart, Ppart, M, jchunk);

    final_fused<<<M / 256, 256, 0, stream>>>(fh, Epart, Ppart, labm, hist,
                                             (float*)d_out, M);
}